// Round 3
// baseline (402.826 us; speedup 1.0000x reference)
//
#include <hip/hip_runtime.h>
#include <stdint.h>

typedef unsigned short bf16u;
typedef float f32x4 __attribute__((ext_vector_type(4)));
typedef short bf16x8 __attribute__((ext_vector_type(8)));
typedef float f4 __attribute__((ext_vector_type(4)));

#define BM 128
#define BN 128
#define BK 64

__device__ __forceinline__ float b2f(bf16u u) {
  union { uint32_t i; float f; } v; v.i = ((uint32_t)u) << 16; return v.f;
}
__device__ __forceinline__ uint32_t f2b(float f) {
  union { float f; uint32_t i; } v; v.f = f;
  uint32_t i = v.i;
  return (i + 0x7FFFu + ((i >> 16) & 1u)) >> 16; // RNE, returns low 16 bits valid
}
__device__ __forceinline__ float sigm(float x) { return 1.f / (1.f + __expf(-x)); }

// ---------------- fp32 -> bf16 conversion (8 elems/thread) ----------------
__global__ __launch_bounds__(256)
void cvt_f32_bf16(const float* __restrict__ src, bf16u* __restrict__ dst) {
  size_t i = ((size_t)blockIdx.x * 256 + threadIdx.x) * 8;
  f4 a = *(const f4*)&src[i];
  f4 b = *(const f4*)&src[i + 4];
  uint4 o;
  o.x = (f2b(a[0]) & 0xffffu) | (f2b(a[1]) << 16);
  o.y = (f2b(a[2]) & 0xffffu) | (f2b(a[3]) << 16);
  o.z = (f2b(b[0]) & 0xffffu) | (f2b(b[1]) << 16);
  o.w = (f2b(b[2]) & 0xffffu) | (f2b(b[3]) << 16);
  *(uint4*)&dst[i] = o;
}

struct GemmPtrs {
  const bf16u* A[3];
  const bf16u* W[3];
  const float* bias[3];
  void* C[3];
};

// C[M,N] = act(A[M,K] @ W[N,K]^T + bias[N]); blockIdx.z selects matrix set.
// A,W bf16; bias fp32; C bf16 or fp32. LDS XOR-swizzled per-row so
// global_load_lds (wave-uniform base + lane*16) coexists with <=2-way conflicts.
template <int ACT, int OUTF32>
__global__ __launch_bounds__(256)
void gemm_bt(GemmPtrs p, int N, int K) {
  __shared__ bf16u sA[BM * BK];
  __shared__ bf16u sB[BN * BK];
  const int z = blockIdx.z;
  const bf16u* __restrict__ A = p.A[z];
  const bf16u* __restrict__ W = p.W[z];
  const float* __restrict__ bias = p.bias[z];

  const int tid  = threadIdx.x;
  const int wave = tid >> 6;
  const int lane = tid & 63;
  const int bn = blockIdx.x, bm = blockIdx.y;

  const int srow = wave * 32 + (lane >> 3);
  const int kc   = (lane & 7) ^ ((lane >> 3) & 7);
  const bf16u* ag = A + (size_t)(bm * BM + srow) * K + kc * 8;
  const bf16u* wg = W + (size_t)(bn * BN + srow) * K + kc * 8;

  const int wm = wave >> 1, wn = wave & 1;  // 2x2 waves of 64x64
  const int q = lane >> 4, cl = lane & 15;

  int aoff[4][2], boff[4][2];
#pragma unroll
  for (int i = 0; i < 4; ++i) {
    int m = wm * 64 + i * 16 + cl;
    int n = wn * 64 + i * 16 + cl;
#pragma unroll
    for (int kk = 0; kk < 2; ++kk) {
      aoff[i][kk] = m * 64 + (((q + kk * 4) ^ (m & 7)) * 8);
      boff[i][kk] = n * 64 + (((q + kk * 4) ^ (n & 7)) * 8);
    }
  }

  f32x4 acc[4][4] = {};

  for (int k0 = 0; k0 < K; k0 += BK) {
#pragma unroll
    for (int t = 0; t < 4; ++t) {
      __builtin_amdgcn_global_load_lds(
          (const __attribute__((address_space(1))) void*)(ag + k0 + (size_t)t * 8 * K),
          (__attribute__((address_space(3))) void*)&sA[wave * 2048 + t * 512],
          16, 0, 0);
      __builtin_amdgcn_global_load_lds(
          (const __attribute__((address_space(1))) void*)(wg + k0 + (size_t)t * 8 * K),
          (__attribute__((address_space(3))) void*)&sB[wave * 2048 + t * 512],
          16, 0, 0);
    }
    __syncthreads();
#pragma unroll
    for (int kk = 0; kk < 2; ++kk) {
      bf16x8 af[4], bfr[4];
#pragma unroll
      for (int i = 0; i < 4; ++i) af[i] = *(const bf16x8*)&sA[aoff[i][kk]];
#pragma unroll
      for (int j = 0; j < 4; ++j) bfr[j] = *(const bf16x8*)&sB[boff[j][kk]];
#pragma unroll
      for (int i = 0; i < 4; ++i)
#pragma unroll
        for (int j = 0; j < 4; ++j)
          acc[i][j] = __builtin_amdgcn_mfma_f32_16x16x32_bf16(af[i], bfr[j], acc[i][j], 0, 0, 0);
    }
    __syncthreads();
  }

  float bv[4];
#pragma unroll
  for (int j = 0; j < 4; ++j)
    bv[j] = bias[bn * BN + wn * 64 + j * 16 + cl];

  const int row0 = bm * BM + wm * 64 + q * 4;
  const int col0 = bn * BN + wn * 64 + cl;
#pragma unroll
  for (int i = 0; i < 4; ++i)
#pragma unroll
    for (int j = 0; j < 4; ++j)
#pragma unroll
      for (int r = 0; r < 4; ++r) {
        float v = acc[i][j][r] + bv[j];
        if (ACT == 1) v = fmaxf(v, 0.f);
        size_t off = (size_t)(row0 + i * 16 + r) * N + (col0 + j * 16);
        if (OUTF32) ((float*)p.C[z])[off] = v;
        else        ((bf16u*)p.C[z])[off] = (bf16u)f2b(v);
      }
}

struct __align__(16) V8 { uint32_t u[4]; };
__device__ __forceinline__ float getf(const V8& v, int k) {
  uint32_t w = v.u[k >> 1];
  return b2f((bf16u)((k & 1) ? (w >> 16) : (w & 0xffffu)));
}
__device__ __forceinline__ void setb(V8& v, int k, float f) {
  uint32_t b = f2b(f) & 0xffffu;
  if (k & 1) v.u[k >> 1] = (v.u[k >> 1] & 0x0000ffffu) | (b << 16);
  else       v.u[k >> 1] = (v.u[k >> 1] & 0xffff0000u) | b;
}

// PyTorch GRU cell gate math (r,z,n order). 8 elems/thread.
// gi/gh bf16 (chunk-local, row stride 3072); hprev fp32; hid_out fp32 (d_out);
// nxt bf16 (feeds next GEMM as A).
template <int LAST>
__global__ __launch_bounds__(256)
void gru_gates(const bf16u* __restrict__ gi, const bf16u* __restrict__ gh,
               const float* __restrict__ hprev, float* __restrict__ hid_out,
               bf16u* __restrict__ nxt) {
  int t = blockIdx.x * 256 + threadIdx.x;
  size_t idx = (size_t)t * 8;
  int b = (int)(idx >> 10);
  int h = (int)(idx & 1023);
  size_t g0 = (size_t)b * 3072 + h;
  V8 ir  = *(const V8*)&gi[g0];
  V8 izv = *(const V8*)&gi[g0 + 1024];
  V8 inv = *(const V8*)&gi[g0 + 2048];
  V8 hr  = *(const V8*)&gh[g0];
  V8 hzv = *(const V8*)&gh[g0 + 1024];
  V8 hnv = *(const V8*)&gh[g0 + 2048];
  f4 hp0 = *(const f4*)&hprev[idx];
  f4 hp1 = *(const f4*)&hprev[idx + 4];
  f4 o0, o1;
  V8 no = {};
#pragma unroll
  for (int k = 0; k < 8; ++k) {
    float hpv = (k < 4) ? hp0[k] : hp1[k - 4];
    float r  = sigm(getf(ir, k) + getf(hr, k));
    float zg = sigm(getf(izv, k) + getf(hzv, k));
    float n  = tanhf(getf(inv, k) + r * getf(hnv, k));
    float hnew = (1.f - zg) * n + zg * hpv;
    if (k < 4) o0[k] = hnew; else o1[k - 4] = hnew;
    setb(no, k, LAST ? tanhf(hnew) : hnew);
  }
  *(f4*)&hid_out[idx] = o0;
  *(f4*)&hid_out[idx + 4] = o1;
  *(V8*)&nxt[idx] = no;
}

// raw: [3][Bc][768] fp32 (mu, sigma, pi), head stride rawHS.
// out fp32: mu | softplus(sigma) | softmax_g(pi), head stride outHS (4096*768).
__global__ __launch_bounds__(256)
void heads_ep(const float* __restrict__ raw, float* __restrict__ out,
              int rawHS, int outHS) {
  int t = blockIdx.x * 256 + threadIdx.x;  // Bc*64 threads, 4 o's each
  int b = t >> 6;
  int o4 = (t & 63) << 2;
  size_t rb = (size_t)b * 768 + o4;
  f4 mu[3], sg[3], pi[3];
#pragma unroll
  for (int g = 0; g < 3; ++g) {
    mu[g] = *(const f4*)&raw[rb + g * 256];
    sg[g] = *(const f4*)&raw[(size_t)rawHS + rb + g * 256];
    pi[g] = *(const f4*)&raw[2 * (size_t)rawHS + rb + g * 256];
  }
  f4 pe[3];
#pragma unroll
  for (int c = 0; c < 4; ++c) {
    float m = fmaxf(fmaxf(pi[0][c], pi[1][c]), pi[2][c]);
    float e0 = __expf(pi[0][c] - m), e1 = __expf(pi[1][c] - m), e2 = __expf(pi[2][c] - m);
    float s = 1.f / (e0 + e1 + e2);
    pe[0][c] = e0 * s; pe[1][c] = e1 * s; pe[2][c] = e2 * s;
  }
#pragma unroll
  for (int g = 0; g < 3; ++g) {
    f4 sp;
#pragma unroll
    for (int c = 0; c < 4; ++c)
      sp[c] = fmaxf(sg[g][c], 0.f) + log1pf(__expf(-fabsf(sg[g][c])));
    *(f4*)&out[rb + g * 256]                     = mu[g];
    *(f4*)&out[(size_t)outHS + rb + g * 256]     = sp;
    *(f4*)&out[2 * (size_t)outHS + rb + g * 256] = pe[g];
  }
}

extern "C" void kernel_launch(void* const* d_in, const int* in_sizes, int n_in,
                              void* d_out, int out_size, void* d_ws, size_t ws_size,
                              hipStream_t stream) {
  const float* x      = (const float*)d_in[0];
  const float* hidden = (const float*)d_in[1];   // [2][4096][1024]
  const float* i2d_w  = (const float*)d_in[2];
  const float* i2d_b  = (const float*)d_in[3];
  const float* w_ih   = (const float*)d_in[4];   // [2][3072][1024]
  const float* w_hh   = (const float*)d_in[5];
  const float* b_ih   = (const float*)d_in[6];   // [2][3072]
  const float* b_hh   = (const float*)d_in[7];
  const float* mu_w   = (const float*)d_in[8];
  const float* mu_b   = (const float*)d_in[9];
  const float* sg_w   = (const float*)d_in[10];
  const float* sg_b   = (const float*)d_in[11];
  const float* pi_w   = (const float*)d_in[12];
  const float* pi_b   = (const float*)d_in[13];
  float* out = (float*)d_out;

  const size_t BH = 4194304;      // 4096*1024
  const int HS = 3145728;         // 4096*768
  float* hid_base = out + (size_t)3 * HS;

  dim3 blk(256, 1, 1);

  // ---- bf16 weight copies at ws start (29.5 MB) ----
  bf16u* wb = (bf16u*)d_ws;
  bf16u* wb_i2d = wb;                       // 524288
  bf16u* wb_ih  = wb_i2d + 524288;          // 6291456 (both layers)
  bf16u* wb_hh  = wb_ih + 6291456;          // 6291456
  bf16u* wb_mu  = wb_hh + 6291456;          // 786432
  bf16u* wb_sg  = wb_mu + 786432;
  bf16u* wb_pi  = wb_sg + 786432;
  const size_t wbytes = 30932992;           // 15466496 elems * 2

  cvt_f32_bf16<<<dim3(524288 / 2048), blk, 0, stream>>>(i2d_w, wb_i2d);
  cvt_f32_bf16<<<dim3(6291456 / 2048), blk, 0, stream>>>(w_ih, wb_ih);
  cvt_f32_bf16<<<dim3(6291456 / 2048), blk, 0, stream>>>(w_hh, wb_hh);
  cvt_f32_bf16<<<dim3(786432 / 2048), blk, 0, stream>>>(mu_w, wb_mu);
  cvt_f32_bf16<<<dim3(786432 / 2048), blk, 0, stream>>>(sg_w, wb_sg);
  cvt_f32_bf16<<<dim3(786432 / 2048), blk, 0, stream>>>(pi_w, wb_pi);

  // ---- per-chunk scratch: Bc*19456 B ----
  // ws0 h1/hnew/hout bf16 Bc*2048B | xb Bc*1024B | hb0 Bc*2048B | hb1 Bc*2048B
  // gi Bc*6144B | gh Bc*6144B ; raw fp32 (Bc*9216B) overlays gi+gh when dead.
  int Bc = 4096;
  while (wbytes + (size_t)Bc * 19456 > ws_size && Bc > 256) Bc >>= 1;
  const int nchunk = 4096 / Bc;

  char* cbase = (char*)d_ws + wbytes;
  bf16u* ws0 = (bf16u*)cbase;
  bf16u* xb  = (bf16u*)(cbase + (size_t)Bc * 2048);
  bf16u* hb0 = (bf16u*)(cbase + (size_t)Bc * 3072);
  bf16u* hb1 = (bf16u*)(cbase + (size_t)Bc * 5120);
  bf16u* gi  = (bf16u*)(cbase + (size_t)Bc * 7168);
  bf16u* gh  = (bf16u*)(cbase + (size_t)Bc * 13312);
  float* raw = (float*)gi;
  const int rawHS = Bc * 768;
  const int gy = Bc / 128;

  for (int c = 0; c < nchunk; ++c) {
    const size_t off = (size_t)c * Bc;
    const float* h0_c = hidden + off * 1024;
    const float* h1_c = hidden + BH + off * 1024;

    cvt_f32_bf16<<<dim3(Bc * 512 / 2048), blk, 0, stream>>>(x + off * 512, xb);
    cvt_f32_bf16<<<dim3(Bc * 1024 / 2048), blk, 0, stream>>>(h0_c, hb0);
    cvt_f32_bf16<<<dim3(Bc * 1024 / 2048), blk, 0, stream>>>(h1_c, hb1);

    { // h1 = relu(x @ i2d_w^T + b)   M=Bc N=1024 K=512
      GemmPtrs p{};
      p.A[0] = xb; p.W[0] = wb_i2d; p.bias[0] = i2d_b; p.C[0] = ws0;
      gemm_bt<1, 0><<<dim3(8, gy, 1), blk, 0, stream>>>(p, 1024, 512);
    }
    { // layer 0 gates: gi = h1 @ w_ih0^T + b ; gh = h0 @ w_hh0^T + b
      GemmPtrs p{};
      p.A[0] = ws0; p.W[0] = wb_ih; p.bias[0] = b_ih; p.C[0] = gi;
      p.A[1] = hb0; p.W[1] = wb_hh; p.bias[1] = b_hh; p.C[1] = gh;
      gemm_bt<0, 0><<<dim3(24, gy, 2), blk, 0, stream>>>(p, 3072, 1024);
    }
    gru_gates<0><<<dim3(Bc / 2), blk, 0, stream>>>(
        gi, gh, h0_c, hid_base + off * 1024, ws0);
    { // layer 1 gates
      GemmPtrs p{};
      p.A[0] = ws0; p.W[0] = wb_ih + 3145728; p.bias[0] = b_ih + 3072; p.C[0] = gi;
      p.A[1] = hb1; p.W[1] = wb_hh + 3145728; p.bias[1] = b_hh + 3072; p.C[1] = gh;
      gemm_bt<0, 0><<<dim3(24, gy, 2), blk, 0, stream>>>(p, 3072, 1024);
    }
    gru_gates<1><<<dim3(Bc / 2), blk, 0, stream>>>(
        gi, gh, h1_c, hid_base + BH + off * 1024, ws0);
    { // heads: raw = h_out @ {mu,sg,pi}_w^T + b   N=768 K=1024, fp32 out
      GemmPtrs p{};
      p.A[0] = ws0; p.W[0] = wb_mu; p.bias[0] = mu_b; p.C[0] = raw;
      p.A[1] = ws0; p.W[1] = wb_sg; p.bias[1] = sg_b; p.C[1] = raw + rawHS;
      p.A[2] = ws0; p.W[2] = wb_pi; p.bias[2] = pi_b; p.C[2] = raw + 2 * (size_t)rawHS;
      gemm_bt<0, 1><<<dim3(6, gy, 3), blk, 0, stream>>>(p, 768, 1024);
    }
    heads_ep<<<dim3(Bc / 4), blk, 0, stream>>>(raw, out + off * 768, rawHS, HS);
  }
}

// Round 4
// 395.715 us; speedup vs baseline: 1.0180x; 1.0180x over previous
//
#include <hip/hip_runtime.h>
#include <stdint.h>

typedef unsigned short bf16u;
typedef float f32x4 __attribute__((ext_vector_type(4)));
typedef short bf16x8 __attribute__((ext_vector_type(8)));
typedef float f4 __attribute__((ext_vector_type(4)));

__device__ __forceinline__ float b2f(bf16u u) {
  union { uint32_t i; float f; } v; v.i = ((uint32_t)u) << 16; return v.f;
}
__device__ __forceinline__ uint32_t f2b(float f) {
  union { float f; uint32_t i; } v; v.f = f;
  uint32_t i = v.i;
  return (i + 0x7FFFu + ((i >> 16) & 1u)) >> 16; // RNE
}
__device__ __forceinline__ float sigm(float x) { return 1.f / (1.f + __expf(-x)); }

// ---------------- multi-segment fp32->bf16 / fp32 copy ----------------
struct CvtSeg { const float* src; char* dst; int blk0; int count; int tobf16; };
struct CvtArgs { CvtSeg s[12]; int nseg; };

__global__ __launch_bounds__(256)
void cvt_multi(CvtArgs a) {
  int b = blockIdx.x, seg = 0;
  while (seg + 1 < a.nseg && b >= a.s[seg + 1].blk0) ++seg;
  const CvtSeg& S = a.s[seg];
  size_t idx = ((size_t)(b - S.blk0) * 2048) + (size_t)threadIdx.x * 8;
  if ((long long)idx >= S.count) return;
  f4 x = *(const f4*)&S.src[idx];
  f4 y = *(const f4*)&S.src[idx + 4];
  if (S.tobf16) {
    uint4 o;
    o.x = (f2b(x[0]) & 0xffffu) | (f2b(x[1]) << 16);
    o.y = (f2b(x[2]) & 0xffffu) | (f2b(x[3]) << 16);
    o.z = (f2b(y[0]) & 0xffffu) | (f2b(y[1]) << 16);
    o.w = (f2b(y[2]) & 0xffffu) | (f2b(y[3]) << 16);
    *(uint4*)((bf16u*)S.dst + idx) = o;
  } else {
    *(f4*)((float*)S.dst + idx) = x;
    *(f4*)((float*)S.dst + idx + 4) = y;
  }
}

// ------------------------------ GEMM ------------------------------
// C[M,N] = act(A[M,K] @ W[N,K]^T + bias[N]).  Tile: (IT*32) x 128, 4 waves,
// wave tile (IT*16) x 64.  LDS XOR-swizzled per-row: slot c of row r holds
// global k-chunk c^(r&7); fragment reads use slot g^(m&7) -> <=2-way conflict.
struct GemmPtrs {
  const bf16u* A[2];
  const bf16u* W[2];
  const float* bias[2];
  void* C[2];
};

template <int IT, int ACT, int OUTF32>
__global__ __launch_bounds__(256)
void gemm_bt(GemmPtrs p, int N, int K) {
  constexpr int BM = IT * 32;
  __shared__ bf16u sA[BM * 64];
  __shared__ bf16u sB[128 * 64];
  const int z = blockIdx.z;
  const bf16u* __restrict__ A = p.A[z];
  const bf16u* __restrict__ W = p.W[z];
  const float* __restrict__ bias = p.bias[z];

  const int tid  = threadIdx.x;
  const int wave = tid >> 6;
  const int lane = tid & 63;
  const int bn = blockIdx.x, bm = blockIdx.y;

  const int srA = wave * (IT * 8) + (lane >> 3);
  const int srB = wave * 32 + (lane >> 3);
  const int kc  = (lane & 7) ^ ((lane >> 3) & 7);
  const bf16u* ag = A + (size_t)(bm * BM + srA) * K + kc * 8;
  const bf16u* wg = W + (size_t)(bn * 128 + srB) * K + kc * 8;

  const int wm = wave >> 1, wn = wave & 1;
  const int q = lane >> 4, cl = lane & 15;

  int aoff[IT][2], boff[4][2];
#pragma unroll
  for (int i = 0; i < IT; ++i) {
    int m = wm * (IT * 16) + i * 16 + cl;
#pragma unroll
    for (int kk = 0; kk < 2; ++kk)
      aoff[i][kk] = m * 64 + (((q + kk * 4) ^ (m & 7)) * 8);
  }
#pragma unroll
  for (int j = 0; j < 4; ++j) {
    int n = wn * 64 + j * 16 + cl;
#pragma unroll
    for (int kk = 0; kk < 2; ++kk)
      boff[j][kk] = n * 64 + (((q + kk * 4) ^ (n & 7)) * 8);
  }

  f32x4 acc[IT][4] = {};

  for (int k0 = 0; k0 < K; k0 += 64) {
#pragma unroll
    for (int t = 0; t < IT; ++t)
      __builtin_amdgcn_global_load_lds(
          (const __attribute__((address_space(1))) void*)(ag + k0 + (size_t)t * 8 * K),
          (__attribute__((address_space(3))) void*)&sA[wave * IT * 512 + t * 512],
          16, 0, 0);
#pragma unroll
    for (int t = 0; t < 4; ++t)
      __builtin_amdgcn_global_load_lds(
          (const __attribute__((address_space(1))) void*)(wg + k0 + (size_t)t * 8 * K),
          (__attribute__((address_space(3))) void*)&sB[wave * 2048 + t * 512],
          16, 0, 0);
    __syncthreads();
#pragma unroll
    for (int kk = 0; kk < 2; ++kk) {
      bf16x8 af[IT], bfr[4];
#pragma unroll
      for (int i = 0; i < IT; ++i) af[i] = *(const bf16x8*)&sA[aoff[i][kk]];
#pragma unroll
      for (int j = 0; j < 4; ++j) bfr[j] = *(const bf16x8*)&sB[boff[j][kk]];
#pragma unroll
      for (int i = 0; i < IT; ++i)
#pragma unroll
        for (int j = 0; j < 4; ++j)
          acc[i][j] = __builtin_amdgcn_mfma_f32_16x16x32_bf16(af[i], bfr[j], acc[i][j], 0, 0, 0);
    }
    __syncthreads();
  }

  float bv[4];
#pragma unroll
  for (int j = 0; j < 4; ++j)
    bv[j] = bias[bn * 128 + wn * 64 + j * 16 + cl];

  const int row0 = bm * BM + wm * (IT * 16) + q * 4;
  const int col0 = bn * 128 + wn * 64 + cl;
#pragma unroll
  for (int i = 0; i < IT; ++i)
#pragma unroll
    for (int j = 0; j < 4; ++j)
#pragma unroll
      for (int r = 0; r < 4; ++r) {
        float v = acc[i][j][r] + bv[j];
        if (ACT == 1) v = fmaxf(v, 0.f);
        size_t off = (size_t)(row0 + i * 16 + r) * N + (col0 + j * 16);
        if (OUTF32) ((float*)p.C[z])[off] = v;
        else        ((bf16u*)p.C[z])[off] = (bf16u)f2b(v);
      }
}

// Heads GEMM: A[M,1024] @ Wp[2304,1024]^T + biasp[2304], packed [mu|sg|pi].
// Tile 64x128; head = bn/6 uniform per block. mu -> out, softplus(sg) -> out+HS,
// pi raw fp32 -> rawpi. Per-head col stride 768.
__global__ __launch_bounds__(256)
void gemm_heads(const bf16u* __restrict__ A, const bf16u* __restrict__ Wp,
                const float* __restrict__ biasp, float* __restrict__ out_mu,
                float* __restrict__ out_sg, float* __restrict__ rawpi,
                int outHS) {
  constexpr int K = 1024;
  __shared__ bf16u sA[64 * 64];
  __shared__ bf16u sB[128 * 64];
  const int tid  = threadIdx.x;
  const int wave = tid >> 6;
  const int lane = tid & 63;
  const int bn = blockIdx.x, bm = blockIdx.y;

  const int srA = wave * 16 + (lane >> 3);
  const int srB = wave * 32 + (lane >> 3);
  const int kc  = (lane & 7) ^ ((lane >> 3) & 7);
  const bf16u* ag = A + (size_t)(bm * 64 + srA) * K + kc * 8;
  const bf16u* wg = Wp + (size_t)(bn * 128 + srB) * K + kc * 8;

  const int wm = wave >> 1, wn = wave & 1;
  const int q = lane >> 4, cl = lane & 15;

  int aoff[2][2], boff[4][2];
#pragma unroll
  for (int i = 0; i < 2; ++i) {
    int m = wm * 32 + i * 16 + cl;
#pragma unroll
    for (int kk = 0; kk < 2; ++kk)
      aoff[i][kk] = m * 64 + (((q + kk * 4) ^ (m & 7)) * 8);
  }
#pragma unroll
  for (int j = 0; j < 4; ++j) {
    int n = wn * 64 + j * 16 + cl;
#pragma unroll
    for (int kk = 0; kk < 2; ++kk)
      boff[j][kk] = n * 64 + (((q + kk * 4) ^ (n & 7)) * 8);
  }

  f32x4 acc[2][4] = {};
  for (int k0 = 0; k0 < K; k0 += 64) {
#pragma unroll
    for (int t = 0; t < 2; ++t)
      __builtin_amdgcn_global_load_lds(
          (const __attribute__((address_space(1))) void*)(ag + k0 + (size_t)t * 8 * K),
          (__attribute__((address_space(3))) void*)&sA[wave * 1024 + t * 512],
          16, 0, 0);
#pragma unroll
    for (int t = 0; t < 4; ++t)
      __builtin_amdgcn_global_load_lds(
          (const __attribute__((address_space(1))) void*)(wg + k0 + (size_t)t * 8 * K),
          (__attribute__((address_space(3))) void*)&sB[wave * 2048 + t * 512],
          16, 0, 0);
    __syncthreads();
#pragma unroll
    for (int kk = 0; kk < 2; ++kk) {
      bf16x8 af[2], bfr[4];
#pragma unroll
      for (int i = 0; i < 2; ++i) af[i] = *(const bf16x8*)&sA[aoff[i][kk]];
#pragma unroll
      for (int j = 0; j < 4; ++j) bfr[j] = *(const bf16x8*)&sB[boff[j][kk]];
#pragma unroll
      for (int i = 0; i < 2; ++i)
#pragma unroll
        for (int j = 0; j < 4; ++j)
          acc[i][j] = __builtin_amdgcn_mfma_f32_16x16x32_bf16(af[i], bfr[j], acc[i][j], 0, 0, 0);
    }
    __syncthreads();
  }

  float bv[4];
#pragma unroll
  for (int j = 0; j < 4; ++j)
    bv[j] = biasp[bn * 128 + wn * 64 + j * 16 + cl];

  const int head = bn / 6;                       // 0:mu 1:sg 2:pi
  const int ch0 = (bn % 6) * 128 + wn * 64 + cl; // col within head
  const int row0 = bm * 64 + wm * 32 + q * 4;
#pragma unroll
  for (int i = 0; i < 2; ++i)
#pragma unroll
    for (int j = 0; j < 4; ++j)
#pragma unroll
      for (int r = 0; r < 4; ++r) {
        float v = acc[i][j][r] + bv[j];
        size_t off = (size_t)(row0 + i * 16 + r) * 768 + (ch0 + j * 16);
        if (head == 0) out_mu[off] = v;
        else if (head == 1)
          out_sg[(size_t)0 + off] = fmaxf(v, 0.f) + log1pf(__expf(-fabsf(v)));
        else rawpi[off] = v;
      }
}

struct __align__(16) V8 { uint32_t u[4]; };
__device__ __forceinline__ float getf(const V8& v, int k) {
  uint32_t w = v.u[k >> 1];
  return b2f((bf16u)((k & 1) ? (w >> 16) : (w & 0xffffu)));
}
__device__ __forceinline__ void setb(V8& v, int k, float f) {
  uint32_t b = f2b(f) & 0xffffu;
  if (k & 1) v.u[k >> 1] = (v.u[k >> 1] & 0x0000ffffu) | (b << 16);
  else       v.u[k >> 1] = (v.u[k >> 1] & 0xffff0000u) | b;
}

// PyTorch GRU cell gate math (r,z,n order). 8 elems/thread.
template <int LAST>
__global__ __launch_bounds__(256)
void gru_gates(const bf16u* __restrict__ gi, const bf16u* __restrict__ gh,
               const float* __restrict__ hprev, float* __restrict__ hid_out,
               bf16u* __restrict__ nxt) {
  int t = blockIdx.x * 256 + threadIdx.x;
  size_t idx = (size_t)t * 8;
  int b = (int)(idx >> 10);
  int h = (int)(idx & 1023);
  size_t g0 = (size_t)b * 3072 + h;
  V8 ir  = *(const V8*)&gi[g0];
  V8 izv = *(const V8*)&gi[g0 + 1024];
  V8 inv = *(const V8*)&gi[g0 + 2048];
  V8 hr  = *(const V8*)&gh[g0];
  V8 hzv = *(const V8*)&gh[g0 + 1024];
  V8 hnv = *(const V8*)&gh[g0 + 2048];
  f4 hp0 = *(const f4*)&hprev[idx];
  f4 hp1 = *(const f4*)&hprev[idx + 4];
  f4 o0, o1;
  V8 no = {};
#pragma unroll
  for (int k = 0; k < 8; ++k) {
    float hpv = (k < 4) ? hp0[k] : hp1[k - 4];
    float r  = sigm(getf(ir, k) + getf(hr, k));
    float zg = sigm(getf(izv, k) + getf(hzv, k));
    float n  = tanhf(getf(inv, k) + r * getf(hnv, k));
    float hnew = (1.f - zg) * n + zg * hpv;
    if (k < 4) o0[k] = hnew; else o1[k - 4] = hnew;
    setb(no, k, LAST ? tanhf(hnew) : hnew);
  }
  *(f4*)&hid_out[idx] = o0;
  *(f4*)&hid_out[idx + 4] = o1;
  *(V8*)&nxt[idx] = no;
}

// softmax over g in {o, o+256, o+512} of rawpi [Bc][768] fp32 -> out fp32.
__global__ __launch_bounds__(256)
void pi_softmax(const float* __restrict__ rawpi, float* __restrict__ out) {
  int t = blockIdx.x * 256 + threadIdx.x;  // Bc*64 threads, 4 o's each
  int b = t >> 6;
  int o4 = (t & 63) << 2;
  size_t rb = (size_t)b * 768 + o4;
  f4 pi0 = *(const f4*)&rawpi[rb];
  f4 pi1 = *(const f4*)&rawpi[rb + 256];
  f4 pi2 = *(const f4*)&rawpi[rb + 512];
  f4 e0v, e1v, e2v;
#pragma unroll
  for (int c = 0; c < 4; ++c) {
    float m = fmaxf(fmaxf(pi0[c], pi1[c]), pi2[c]);
    float e0 = __expf(pi0[c] - m), e1 = __expf(pi1[c] - m), e2 = __expf(pi2[c] - m);
    float s = 1.f / (e0 + e1 + e2);
    e0v[c] = e0 * s; e1v[c] = e1 * s; e2v[c] = e2 * s;
  }
  *(f4*)&out[rb]       = e0v;
  *(f4*)&out[rb + 256] = e1v;
  *(f4*)&out[rb + 512] = e2v;
}

extern "C" void kernel_launch(void* const* d_in, const int* in_sizes, int n_in,
                              void* d_out, int out_size, void* d_ws, size_t ws_size,
                              hipStream_t stream) {
  const float* x      = (const float*)d_in[0];
  const float* hidden = (const float*)d_in[1];   // [2][4096][1024]
  const float* i2d_w  = (const float*)d_in[2];
  const float* i2d_b  = (const float*)d_in[3];
  const float* w_ih   = (const float*)d_in[4];   // [2][3072][1024]
  const float* w_hh   = (const float*)d_in[5];
  const float* b_ih   = (const float*)d_in[6];
  const float* b_hh   = (const float*)d_in[7];
  const float* mu_w   = (const float*)d_in[8];
  const float* mu_b   = (const float*)d_in[9];
  const float* sg_w   = (const float*)d_in[10];
  const float* sg_b   = (const float*)d_in[11];
  const float* pi_w   = (const float*)d_in[12];
  const float* pi_b   = (const float*)d_in[13];
  float* out = (float*)d_out;

  const size_t BH = 4194304;      // 4096*1024
  const int HS = 3145728;         // 4096*768
  float* hid_base = out + (size_t)3 * HS;

  dim3 blk(256, 1, 1);

  // ---- ws: bf16 weights (29.5 MB) + packed head bias fp32 ----
  bf16u* wb_i2d = (bf16u*)d_ws;             // 524288
  bf16u* wb_ih  = wb_i2d + 524288;          // 6291456 (both layers)
  bf16u* wb_hh  = wb_ih + 6291456;          // 6291456
  bf16u* wb_hd  = wb_hh + 6291456;          // 2359296 packed [mu|sg|pi][768][1024]
  float* biasp  = (float*)((char*)d_ws + 30932992);  // 2304 fp32
  const size_t wbytes = 30942208;

  { // one dispatch: 6 weight cvts + 3 bias copies
    CvtArgs a{};
    int nb = 0;
    auto seg = [&](const float* s, void* d, int count, int tobf) {
      a.s[a.nseg++] = {s, (char*)d, nb, count, tobf};
      nb += (count + 2047) / 2048;
    };
    seg(i2d_w, wb_i2d, 524288, 1);
    seg(w_ih,  wb_ih, 6291456, 1);
    seg(w_hh,  wb_hh, 6291456, 1);
    seg(mu_w,  wb_hd, 786432, 1);
    seg(sg_w,  wb_hd + 786432, 786432, 1);
    seg(pi_w,  wb_hd + 1572864, 786432, 1);
    seg(mu_b,  biasp, 768, 0);
    seg(sg_b,  biasp + 768, 768, 0);
    seg(pi_b,  biasp + 1536, 768, 0);
    cvt_multi<<<dim3(nb), blk, 0, stream>>>(a);
  }

  // ---- per-chunk scratch: Bc*19456 B ----
  int Bc = 4096;
  while (wbytes + (size_t)Bc * 19456 > ws_size && Bc > 256) Bc >>= 1;
  const int nchunk = 4096 / Bc;

  char* cbase = (char*)d_ws + wbytes;
  bf16u* ws0 = (bf16u*)cbase;                          // h1/hnew/hout bf16
  bf16u* xb  = (bf16u*)(cbase + (size_t)Bc * 2048);
  bf16u* hb0 = (bf16u*)(cbase + (size_t)Bc * 3072);
  bf16u* hb1 = (bf16u*)(cbase + (size_t)Bc * 5120);
  bf16u* gi  = (bf16u*)(cbase + (size_t)Bc * 7168);
  bf16u* gh  = (bf16u*)(cbase + (size_t)Bc * 13312);
  float* rawpi = (float*)gi;  // Bc*3072B, overlays dead gi

  for (int c = 0; c < nchunk; ++c) {
    const size_t off = (size_t)c * Bc;
    const float* h0_c = hidden + off * 1024;
    const float* h1_c = hidden + BH + off * 1024;

    { // one dispatch: x, h0, h1 cvt
      CvtArgs a{};
      int nb = 0;
      auto seg = [&](const float* s, void* d, int count) {
        a.s[a.nseg++] = {s, (char*)d, nb, count, 1};
        nb += (count + 2047) / 2048;
      };
      seg(x + off * 512, xb, Bc * 512);
      seg(h0_c, hb0, Bc * 1024);
      seg(h1_c, hb1, Bc * 1024);
      cvt_multi<<<dim3(nb), blk, 0, stream>>>(a);
    }

    { // h1 = relu(x @ i2d_w^T + b)  M=Bc N=1024 K=512, 64x128 tiles
      GemmPtrs p{};
      p.A[0] = xb; p.W[0] = wb_i2d; p.bias[0] = i2d_b; p.C[0] = ws0;
      gemm_bt<2, 1, 0><<<dim3(8, Bc / 64, 1), blk, 0, stream>>>(p, 1024, 512);
    }
    { // layer 0 gates
      GemmPtrs p{};
      p.A[0] = ws0; p.W[0] = wb_ih; p.bias[0] = b_ih; p.C[0] = gi;
      p.A[1] = hb0; p.W[1] = wb_hh; p.bias[1] = b_hh; p.C[1] = gh;
      gemm_bt<4, 0, 0><<<dim3(24, Bc / 128, 2), blk, 0, stream>>>(p, 3072, 1024);
    }
    gru_gates<0><<<dim3(Bc / 2), blk, 0, stream>>>(
        gi, gh, h0_c, hid_base + off * 1024, ws0);
    { // layer 1 gates
      GemmPtrs p{};
      p.A[0] = ws0; p.W[0] = wb_ih + 3145728; p.bias[0] = b_ih + 3072; p.C[0] = gi;
      p.A[1] = hb1; p.W[1] = wb_hh + 3145728; p.bias[1] = b_hh + 3072; p.C[1] = gh;
      gemm_bt<4, 0, 0><<<dim3(24, Bc / 128, 2), blk, 0, stream>>>(p, 3072, 1024);
    }
    gru_gates<1><<<dim3(Bc / 2), blk, 0, stream>>>(
        gi, gh, h1_c, hid_base + BH + off * 1024, ws0);
    // heads: 64x128 tiles, packed N=2304; mu/softplus direct, pi to raw
    gemm_heads<<<dim3(18, Bc / 64, 1), blk, 0, stream>>>(
        ws0, wb_hd, biasp, out + off * 768, out + HS + off * 768, rawpi, HS);
    pi_softmax<<<dim3(Bc / 4), blk, 0, stream>>>(rawpi, out + 2 * (size_t)HS + off * 768);
  }
}